// Round 14
// baseline (287.605 us; speedup 1.0000x reference)
//
#include <hip/hip_runtime.h>

// UAG_RNN v17: v16 at 8 blocks/chain (all 256 CUs).
//  Refined model (R13): T_step ~= bytes_per_CU / ~8-10.5 B/cy + ~800cy
//  (v8 80KB->7470, v16 30KB->3670; shuffle term was ~1300cy of v13).
//  Next notch on the only lever that ever moved big (R8): halve per-CU
//  bytes again. 8 blocks/chain, 16 owned + 16 halo rows, 2 waves/block.
//  Same halo margin as v16 (16-row halo / 16-step refresh). Seam overlay
//  grows to 4.2MB (< dead-x2 16.8MB). Chain's 8 blocks share an XCD.
// B=8, C=64, H=128, W=128.

#define B_ 8
#define C_ 64
#define H_ 128
#define W_ 128
#define HW_ (H_*W_)      // 16384
#define CHW_ (C_*HW_)    // 1048576
#define TOT_ (B_*CHW_)   // 8388608

typedef __attribute__((ext_vector_type(8))) short bfrag;
typedef __attribute__((ext_vector_type(4))) float f4_t;

__device__ inline unsigned short bfr(float f) {
    unsigned int u = __float_as_uint(f);
    u += 0x7fffu + ((u >> 16) & 1u);
    return (unsigned short)(u >> 16);
}
__device__ inline float b2f(unsigned short u) {
    return __uint_as_float(((unsigned int)u) << 16);
}
__device__ inline bfrag packf(float4 a, float4 b) {
    bfrag r;
    r[0]=(short)bfr(a.x); r[1]=(short)bfr(a.y); r[2]=(short)bfr(a.z); r[3]=(short)bfr(a.w);
    r[4]=(short)bfr(b.x); r[5]=(short)bfr(b.y); r[6]=(short)bfr(b.z); r[7]=(short)bfr(b.w);
    return r;
}
__device__ inline ushort4 pack4(float a, float b, float c, float d) {
    ushort4 r; r.x=bfr(a); r.y=bfr(b); r.z=bfr(c); r.w=bfr(d); return r;
}
__device__ inline unsigned int relu2(unsigned int w) {
    unsigned int lo = (w & 0x8000u) ? 0u : (w & 0xffffu);
    unsigned int hi = (w & 0x80000000u) ? 0u : (w & 0xffff0000u);
    return lo | hi;
}
__device__ inline uint4 relu8(uint4 v) {
    v.x = relu2(v.x); v.y = relu2(v.y); v.z = relu2(v.z); v.w = relu2(v.w);
    return v;
}

#define MFMA __builtin_amdgcn_mfma_f32_16x16x32_bf16

// lgkm-only barrier, NO memory clobber (v9/v12/v13/v16-proven): 0xC07F =
// vmcnt(63) expcnt(7) lgkmcnt(0). Orders LDS across waves; vmem in flight.
#define SBAR_LGKM() do { \
    __builtin_amdgcn_sched_barrier(0); \
    __builtin_amdgcn_s_waitcnt(0xC07F); \
    __builtin_amdgcn_s_barrier(); \
    __builtin_amdgcn_sched_barrier(0); \
} while (0)

// x NCHW fp32 -> x2 NHWC(h-major) bf16
// y NCHW fp32 -> y2 NHWC(h-major) fp32  AND  y2T NHWC(w-major) fp32
__global__ void k_prep(const float* __restrict__ x, const float* __restrict__ y,
                       float* __restrict__ y2, float* __restrict__ y2T,
                       unsigned short* __restrict__ x2) {
    __shared__ float t[64][65];
    int blk = blockIdx.x;
    int isx = blk >> 11; blk &= 2047;
    int b = blk >> 8, hw0 = (blk & 255) * 64;
    int cq = threadIdx.x >> 6, lo = threadIdx.x & 63;
    const float* ip = (isx ? x : y) + (size_t)b * CHW_;
#pragma unroll
    for (int p = 0; p < 16; p++) {
        int c = p * 4 + cq;
        t[c][lo] = ip[(size_t)c * HW_ + hw0 + lo];
    }
    __syncthreads();
    if (isx) {
        unsigned short* op = x2 + (size_t)b * CHW_;
#pragma unroll
        for (int p = 0; p < 16; p++) {
            int hw = p * 4 + cq;
            op[(size_t)(hw0 + hw) * 64 + lo] = bfr(t[lo][hw]);
        }
    } else {
        float* op = y2 + (size_t)b * CHW_;
        float* opT = y2T + (size_t)b * CHW_;
#pragma unroll
        for (int p = 0; p < 16; p++) {
            int hw = p * 4 + cq;
            int P = hw0 + hw;
            int h = P >> 7, w = P & 127;
            float v = t[lo][hw];
            op[(size_t)P * 64 + lo] = v;
            opT[(size_t)((w << 7) | h) * 64 + lo] = v;
        }
    }
}

// sum 4 fp32 NHWC(h-major) dir buffers -> out NCHW fp32
__global__ void k_tb(const float* __restrict__ i0, const float* __restrict__ i1,
                     const float* __restrict__ i2, const float* __restrict__ i3,
                     float* __restrict__ outp) {
    __shared__ float t[64][65];
    int blk = blockIdx.x;
    int b = blk >> 8, hw0 = (blk & 255) * 64;
    int cq = threadIdx.x >> 6, lo = threadIdx.x & 63;
    size_t bb = (size_t)b * CHW_;
#pragma unroll
    for (int p = 0; p < 16; p++) {
        int hw = p * 4 + cq;
        size_t s = bb + (size_t)(hw0 + hw) * 64 + lo;
        t[hw][lo] = i0[s] + i1[s] + i2[s] + i3[s];
    }
    __syncthreads();
    float* op = outp + bb;
#pragma unroll
    for (int p = 0; p < 16; p++) {
        int c = p * 4 + cq;
        op[(size_t)c * HW_ + hw0 + lo] = t[lo][c];
    }
}

// ---------------- row scans ----------------
struct PrefR { uint4 x0, x1; float4 yv[4]; };

__device__ __forceinline__ void row_step(
        int i, int s, int w0, int q, int n,
        const unsigned short* __restrict__ xb, const float* __restrict__ yb,
        unsigned short* __restrict__ dT,
        unsigned short (&stt)[2][16][72],
        const bfrag (&WaF)[4][2], const bfrag (&WbF)[4][2],
        const f4_t (&cA)[4], const f4_t (&cB)[4],
        PrefR& cur, PrefR& nxt) {
    int row = s ? 127 - i : i;
    int rd = (i - 1) & 1, wr = i & 1;

    bfrag fb0 = *(const bfrag*)&stt[rd][n][q * 8];
    bfrag fb1 = *(const bfrag*)&stt[rd][n][32 + q * 8];
    bfrag fa0 = *(const bfrag*)&cur.x0;
    bfrag fa1 = *(const bfrag*)&cur.x1;

    f4_t DA[4], DB[4];
#pragma unroll
    for (int mt = 0; mt < 4; mt++) {
        DA[mt] = MFMA(WaF[mt][0], fa0, cA[mt], 0, 0, 0);
        DA[mt] = MFMA(WaF[mt][1], fa1, DA[mt], 0, 0, 0);
        DB[mt] = MFMA(WbF[mt][0], fb0, cB[mt], 0, 0, 0);
        DB[mt] = MFMA(WbF[mt][1], fb1, DB[mt], 0, 0, 0);
    }

    if (i < 127) {
        int rowN = s ? 126 - i : i + 1;
        int yrowN = s ? rowN + 1 : rowN - 1;
        const unsigned short* sp = xb + (size_t)(rowN * 128 + w0 + n) * 64 + q * 8;
        nxt.x0 = *(const uint4*)sp;
        nxt.x1 = *(const uint4*)(sp + 32);
#pragma unroll
        for (int mt = 0; mt < 4; mt++)
            nxt.yv[mt] = *(const float4*)&yb[(size_t)(yrowN * 128 + w0 + n) * 64 + mt * 16 + q * 4];
    }

#pragma unroll
    for (int mt = 0; mt < 4; mt++) {
        float h0 = fmaxf(DA[mt][0] + DB[mt][0] * cur.yv[mt].x, 0.f);
        float h1 = fmaxf(DA[mt][1] + DB[mt][1] * cur.yv[mt].y, 0.f);
        float h2 = fmaxf(DA[mt][2] + DB[mt][2] * cur.yv[mt].z, 0.f);
        float h3 = fmaxf(DA[mt][3] + DB[mt][3] * cur.yv[mt].w, 0.f);
        ushort4 pk = pack4(h0, h1, h2, h3);
        *(ushort4*)&stt[wr][n][mt * 16 + q * 4] = pk;
        // w-major output: ((w)*128 + h)*64 + ch   (colscan reads columns!)
        *(ushort4*)&dT[(size_t)((w0 + n) * 128 + row) * 64 + mt * 16 + q * 4] = pk;
    }
}

// grid 128 = s(2) x b(8) x wb(8 of width 16). 1 wave/block.
__global__ __launch_bounds__(64, 1) void k_rowscan(
        const unsigned short* __restrict__ x2, const float* __restrict__ y2,
        const float* __restrict__ Wc, const float* __restrict__ bc,
        unsigned short* __restrict__ hsT, unsigned short* __restrict__ hnT) {
    int bid = blockIdx.x;
    int s = bid >> 6, b = (bid >> 3) & 7, wb = bid & 7;
    int w0 = wb * 16;
    int lane = threadIdx.x, q = lane >> 4, n = lane & 15;
    int ka = s ? 8 : 0, kb = ka + 1;

    bfrag WaF[4][2], WbF[4][2];
#pragma unroll
    for (int mt = 0; mt < 4; mt++)
#pragma unroll
        for (int kc = 0; kc < 2; kc++) {
            const float* wp = Wc + (size_t)(ka * 64 + mt * 16 + n) * 64 + kc * 32 + q * 8;
            WaF[mt][kc] = packf(*(const float4*)wp, *(const float4*)(wp + 4));
            const float* wq2 = Wc + (size_t)(kb * 64 + mt * 16 + n) * 64 + kc * 32 + q * 8;
            WbF[mt][kc] = packf(*(const float4*)wq2, *(const float4*)(wq2 + 4));
        }
    f4_t cA[4], cB[4];
#pragma unroll
    for (int mt = 0; mt < 4; mt++) {
        float4 ta = *(const float4*)&bc[ka * 64 + mt * 16 + q * 4];
        float4 tb = *(const float4*)&bc[kb * 64 + mt * 16 + q * 4];
        cA[mt] = f4_t{ta.x, ta.y, ta.z, ta.w};
        cB[mt] = f4_t{tb.x, tb.y, tb.z, tb.w};
    }

    const unsigned short* xb = x2 + (size_t)b * CHW_;
    const float* yb = y2 + (size_t)b * CHW_;
    unsigned short* dT = (s ? hnT : hsT) + (size_t)b * CHW_;

    __shared__ __align__(16) unsigned short stt[2][16][72];

    int row0 = s ? 127 : 0;
    {
        const unsigned short* sp = xb + (size_t)(row0 * 128 + w0 + n) * 64 + q * 16;
        uint4 v0 = *(const uint4*)sp;
        uint4 v1 = *(const uint4*)(sp + 8);
        if (s) { v0 = relu8(v0); v1 = relu8(v1); }
        *(uint4*)&stt[0][n][q * 16] = v0;
        *(uint4*)&stt[0][n][q * 16 + 8] = v1;
        unsigned short* op = dT + (size_t)((w0 + n) * 128 + row0) * 64 + q * 16;
        *(uint4*)op = v0;
        *(uint4*)(op + 8) = v1;
    }

    PrefR Pa, Pb;
    {
        int row1 = s ? 126 : 1;
        const unsigned short* sp = xb + (size_t)(row1 * 128 + w0 + n) * 64 + q * 8;
        Pa.x0 = *(const uint4*)sp;
        Pa.x1 = *(const uint4*)(sp + 32);
#pragma unroll
        for (int mt = 0; mt < 4; mt++)
            Pa.yv[mt] = *(const float4*)&yb[(size_t)(row0 * 128 + w0 + n) * 64 + mt * 16 + q * 4];
    }

    for (int i = 1; i < 127; i += 2) {
        row_step(i,     s, w0, q, n, xb, yb, dT, stt, WaF, WbF, cA, cB, Pa, Pb);
        row_step(i + 1, s, w0, q, n, xb, yb, dT, stt, WaF, WbF, cA, cB, Pb, Pa);
    }
    row_step(127, s, w0, q, n, xb, yb, dT, stt, WaF, WbF, cA, cB, Pa, Pb);
}

// ---------------- col scans (8 blocks/chain, halo, shuffle-free) --------
// grid 256 = k(8) x d(4) x b(8); bid = k*32 + d*8 + b (chain blocks share
// an XCD: bid mod 8 == b). 128 threads = 2 waves of 16 rows each. Block k:
// rows [base_row, base_row+32), base_row = down ? 16k-16 : 16k.
// down: g0 = halo (above), g1 owned. up: g0 owned, g1 = halo (below).
// Halo refresh at j=16,32,...,112 (16-row halo = 16-step margin).
struct PrefC { uint4 b0, b1; float4 yr[4], ys[4]; };

__device__ __forceinline__ void cpre(
        int p, int flip, int q, int Rc, int Rsh,
        const unsigned short* __restrict__ baseT, const float* __restrict__ yT,
        PrefC& dst) {
    if (p > 127) return;
    int cjP = flip ? 127 - p : p;
    int ycP = flip ? 128 - p : p - 1;
    const unsigned short* sp = baseT + (size_t)(cjP * 128 + Rc) * 64 + q * 8;
    dst.b0 = *(const uint4*)sp;
    dst.b1 = *(const uint4*)(sp + 32);
#pragma unroll
    for (int mt = 0; mt < 4; mt++) {
        dst.yr[mt] = *(const float4*)&yT[(size_t)(ycP * 128 + Rc) * 64 + mt * 16 + q * 4];
        dst.ys[mt] = *(const float4*)&yT[(size_t)(ycP * 128 + Rsh) * 64 + mt * 16 + q * 4];
    }
}

__device__ __forceinline__ void cstep(
        int j, int pcol, int flip, int down, int k, int g, int base_row,
        int q, int n, float gmv, int Rsh,
        const unsigned short* __restrict__ baseT, const float* __restrict__ yT,
        float* __restrict__ oB,
        unsigned short (&stt)[2][34][72],
        const bfrag (&WA)[4][2], const bfrag (&WB)[4][2], const bfrag (&WT)[4][2],
        const f4_t (&cAr)[4], const f4_t (&cBr)[4], const f4_t (&cTr)[4],
        unsigned int* __restrict__ flags, ushort4* __restrict__ seamD, int cidx,
        bool ownedW, bool pubW, bool rdrW,
        PrefC& cur, PrefC& nxt) {
    int cj = flip ? 127 - j : j;
    int rd = (j - 1) & 1, wr = j & 1;
    int R  = base_row + g * 16 + n;
    int Rc = R < 0 ? 0 : (R > 127 ? 127 : R);
    int L  = g * 16 + n + 1;
    float gT = ((down ? (R == 0) : (R == 127)) ? 0.f : gmv);
    bool syncstep = ((j & 15) == 0) && (j <= 112);

    // ---- issue stream loads for column pcol (= j+2), 2 steps of cover
    cpre(pcol, flip, q, Rc, Rsh, baseT, yT, nxt);

    // ---- LDS state reads
    bfrag fb0 = *(const bfrag*)&stt[rd][L][q * 8];
    bfrag fb1 = *(const bfrag*)&stt[rd][L][32 + q * 8];
    int Ls = down ? (L - 1) : (L + 1);
    bfrag ft0 = *(const bfrag*)&stt[rd][Ls][q * 8];
    bfrag ft1 = *(const bfrag*)&stt[rd][Ls][32 + q * 8];
    bfrag fa0 = *(const bfrag*)&cur.b0;
    bfrag fa1 = *(const bfrag*)&cur.b1;

    f4_t DA[4], DB[4], DT[4];
#pragma unroll
    for (int mt = 0; mt < 4; mt++) {
        DA[mt] = MFMA(WA[mt][0], fa0, cAr[mt], 0, 0, 0);
        DA[mt] = MFMA(WA[mt][1], fa1, DA[mt], 0, 0, 0);
        DB[mt] = MFMA(WB[mt][0], fb0, cBr[mt], 0, 0, 0);
        DB[mt] = MFMA(WB[mt][1], fb1, DB[mt], 0, 0, 0);
        DT[mt] = MFMA(WT[mt][0], ft0, cTr[mt], 0, 0, 0);
        DT[mt] = MFMA(WT[mt][1], ft1, DT[mt], 0, 0, 0);
    }

    size_t slotP = ((size_t)(cidx * 8 + k) * 8 + (j >> 4)) - 1;  // publisher slot

    // ---- finalize: h = relu(DA + DB*yr + gT*(DT*ys)); no shuffles.
#pragma unroll
    for (int mt = 0; mt < 4; mt++) {
        float4 yr4 = cur.yr[mt];
        float4 ys4 = cur.ys[mt];
        float h0 = fmaxf(DA[mt][0] + DB[mt][0] * yr4.x + gT * (DT[mt][0] * ys4.x), 0.f);
        float h1 = fmaxf(DA[mt][1] + DB[mt][1] * yr4.y + gT * (DT[mt][1] * ys4.y), 0.f);
        float h2 = fmaxf(DA[mt][2] + DB[mt][2] * yr4.z + gT * (DT[mt][2] * ys4.z), 0.f);
        float h3 = fmaxf(DA[mt][3] + DB[mt][3] * yr4.w + gT * (DT[mt][3] * ys4.w), 0.f);
        ushort4 pk = pack4(h0, h1, h2, h3);
        *(ushort4*)&stt[wr][L][mt * 16 + q * 4] = pk;
        if (ownedW)
            *(float4*)&oB[(size_t)(R * 128 + cj) * 64 + mt * 16 + q * 4] =
                make_float4(h0, h1, h2, h3);
        if (pubW && syncstep)
            seamD[slotP * 256 + n * 16 + mt * 4 + q] = pk;
    }

    // ---- halo refresh protocol (every 16 columns; amortized)
    if (syncstep) {
        if (pubW && n == 0 && q == 0)
            __hip_atomic_store(&flags[slotP], 1u, __ATOMIC_RELEASE,
                               __HIP_MEMORY_SCOPE_AGENT);
        if (rdrW) {
            int kk = down ? k - 1 : k + 1;
            size_t slotR = ((size_t)(cidx * 8 + kk) * 8 + (j >> 4)) - 1;
            unsigned int guard = 0;
            while (__hip_atomic_load(&flags[slotR], __ATOMIC_ACQUIRE,
                                     __HIP_MEMORY_SCOPE_AGENT) == 0u)
                if (++guard > (1u << 22)) break;
#pragma unroll
            for (int mt = 0; mt < 4; mt++) {
                ushort4 sv = seamD[slotR * 256 + n * 16 + mt * 4 + q];
                *(ushort4*)&stt[wr][L][mt * 16 + q * 4] = sv;
            }
        }
    }
    SBAR_LGKM();
}

// grid 256 = k(8) x d(4) x b(8). 128 threads = 2 waves.
__global__ __launch_bounds__(128, 1) void k_colscan(
        const float* __restrict__ y2T,
        const unsigned short* __restrict__ hsT, const unsigned short* __restrict__ hnT,
        const float* __restrict__ Wc, const float* __restrict__ bc,
        const float* __restrict__ gam,
        unsigned int* __restrict__ flags, ushort4* __restrict__ seamD,
        float* __restrict__ outD) {
    int bid = blockIdx.x;
    int k = bid >> 5, d = (bid >> 3) & 3, b = bid & 7;
    int tid = threadIdx.x;
    int g = tid >> 6, lane = tid & 63, q = lane >> 4, n = lane & 15;
    int down = (d < 2) ? 1 : 0;
    int flip = d & 1;
    int cidx = d * 8 + b;
    int base_row = down ? 16 * k - 16 : 16 * k;
    bool ownedW = down ? (g == 1) : (g == 0);
    bool pubW = down ? (g == 1 && k < 7) : (g == 0 && k > 0);
    bool rdrW = down ? (g == 0 && k > 0) : (g == 1 && k < 7);
    const unsigned short* baseT = ((d < 2) ? hsT : hnT) + (size_t)b * CHW_;
    int kt, ka, kb;
    if (d == 0)      { kt = 2;  ka = 3;  kb = 4;  }
    else if (d == 1) { kt = 5;  ka = 6;  kb = 7;  }
    else if (d == 2) { kt = 10; ka = 11; kb = 12; }
    else             { kt = 13; ka = 14; kb = 15; }
    float gmv = gam[d];

    bfrag WA[4][2], WB[4][2], WT[4][2];
#pragma unroll
    for (int mt = 0; mt < 4; mt++)
#pragma unroll
        for (int kc = 0; kc < 2; kc++) {
            const float* wa = Wc + (size_t)(ka * 64 + mt * 16 + n) * 64 + kc * 32 + q * 8;
            const float* wb = Wc + (size_t)(kb * 64 + mt * 16 + n) * 64 + kc * 32 + q * 8;
            const float* wt = Wc + (size_t)(kt * 64 + mt * 16 + n) * 64 + kc * 32 + q * 8;
            WA[mt][kc] = packf(*(const float4*)wa, *(const float4*)(wa + 4));
            WB[mt][kc] = packf(*(const float4*)wb, *(const float4*)(wb + 4));
            WT[mt][kc] = packf(*(const float4*)wt, *(const float4*)(wt + 4));
        }
    f4_t cAr[4], cBr[4], cTr[4];
#pragma unroll
    for (int mt = 0; mt < 4; mt++) {
        float4 ta = *(const float4*)&bc[ka * 64 + mt * 16 + q * 4];
        float4 tb = *(const float4*)&bc[kb * 64 + mt * 16 + q * 4];
        float4 tt = *(const float4*)&bc[kt * 64 + mt * 16 + q * 4];
        cAr[mt] = f4_t{ta.x, ta.y, ta.z, ta.w};
        cBr[mt] = f4_t{tb.x, tb.y, tb.z, tb.w};
        cTr[mt] = f4_t{tt.x, tt.y, tt.z, tt.w};
    }

    const float* yT = y2T + (size_t)b * CHW_;
    float* oB = outD + (size_t)d * TOT_ + (size_t)b * CHW_;

    int R = base_row + g * 16 + n;
    int Rc = R < 0 ? 0 : (R > 127 ? 127 : R);
    int Rsh = R + (down ? -1 : 1);
    Rsh = Rsh < 0 ? 0 : (Rsh > 127 ? 127 : Rsh);
    int L = g * 16 + n + 1;

    __shared__ __align__(16) unsigned short stt[2][34][72];  // pads at 0 and 33
    for (int idx = tid; idx < 2 * 2 * 72; idx += 128) {
        int buf = idx / 144, hi = (idx / 72) & 1, t = idx % 72;
        stt[buf][hi ? 33 : 0][t] = 0;
    }

    // ---- j = 0 : c0 = relu(base col0) for all 32 rows (halo incl.)
    int c0 = flip ? 127 : 0;
    {
        const unsigned short* sp = baseT + (size_t)(c0 * 128 + Rc) * 64 + q * 16;
        uint4 v0 = relu8(*(const uint4*)sp);
        uint4 v1 = relu8(*(const uint4*)(sp + 8));
        *(uint4*)&stt[0][L][q * 16] = v0;
        *(uint4*)&stt[0][L][q * 16 + 8] = v1;
        if (ownedW) {
            float* op = oB + (size_t)(R * 128 + c0) * 64 + q * 16;
            unsigned int w8[8] = {v0.x, v0.y, v0.z, v0.w, v1.x, v1.y, v1.z, v1.w};
#pragma unroll
            for (int t = 0; t < 8; t++) {
                op[2 * t]     = b2f((unsigned short)(w8[t] & 0xffffu));
                op[2 * t + 1] = b2f((unsigned short)(w8[t] >> 16));
            }
        }
    }

    // prefetch ring: Pa <- col 1, Pb <- col 2
    PrefC Pa, Pb, Pc;
    cpre(1, flip, q, Rc, Rsh, baseT, yT, Pa);
    cpre(2, flip, q, Rc, Rsh, baseT, yT, Pb);
    SBAR_LGKM();

    // steps j=1..126 in triples; j consumes set(j), issues set for j+2.
    for (int j = 1; j <= 124; j += 3) {
        cstep(j,     j + 2, flip, down, k, g, base_row, q, n, gmv, Rsh,
              baseT, yT, oB, stt, WA, WB, WT, cAr, cBr, cTr,
              flags, seamD, cidx, ownedW, pubW, rdrW, Pa, Pc);
        cstep(j + 1, j + 3, flip, down, k, g, base_row, q, n, gmv, Rsh,
              baseT, yT, oB, stt, WA, WB, WT, cAr, cBr, cTr,
              flags, seamD, cidx, ownedW, pubW, rdrW, Pb, Pa);
        cstep(j + 2, j + 4, flip, down, k, g, base_row, q, n, gmv, Rsh,
              baseT, yT, oB, stt, WA, WB, WT, cAr, cBr, cTr,
              flags, seamD, cidx, ownedW, pubW, rdrW, Pc, Pb);
    }
    // tail: j = 127 consumes Pa (filled by cstep(125)'s pcol=127)
    cstep(127, 129, flip, down, k, g, base_row, q, n, gmv, Rsh,
          baseT, yT, oB, stt, WA, WB, WT, cAr, cBr, cTr,
          flags, seamD, cidx, ownedW, pubW, rdrW, Pa, Pb);
}

extern "C" void kernel_launch(void* const* d_in, const int* in_sizes, int n_in,
                              void* d_out, int out_size, void* d_ws, size_t ws_size,
                              hipStream_t stream) {
    const float* x   = (const float*)d_in[0];
    const float* y   = (const float*)d_in[1];
    const float* Wc  = (const float*)d_in[2];
    const float* bc  = (const float*)d_in[3];
    const float* gam = (const float*)d_in[4];
    float* out = (float*)d_out;

    // ws layout: x2 bf16 (16.8M), y2 fp32 (33.6M), y2T fp32 (33.6M),
    // hsT/hnT bf16 (16.8M ea), outD fp32 x4 (134.2M). Seam flags (64KB) +
    // seam data (4.2MB) overlay x2 (dead after rowscan; memset stream-ordered).
    unsigned short* x2 = (unsigned short*)d_ws;
    float* y2  = (float*)d_ws + (size_t)TOT_ / 2;
    float* y2T = y2 + (size_t)TOT_;
    unsigned short* hsT = (unsigned short*)(y2T + (size_t)TOT_);
    unsigned short* hnT = hsT + (size_t)TOT_;
    float* outD = (float*)(hnT + (size_t)TOT_);
    unsigned int* flags = (unsigned int*)d_ws;                       // 8 KB used
    ushort4* seamD = (ushort4*)((char*)d_ws + 65536);                // ~4.2 MB

    hipLaunchKernelGGL(k_prep, dim3(4096), dim3(256), 0, stream, x, y, y2, y2T, x2);
    hipLaunchKernelGGL(k_rowscan, dim3(128), dim3(64), 0, stream, x2, y2, Wc, bc, hsT, hnT);
    hipMemsetAsync(flags, 0, 65536, stream);
    hipLaunchKernelGGL(k_colscan, dim3(256), dim3(128), 0, stream,
                       y2T, hsT, hnT, Wc, bc, gam, flags, seamD, outD);
    hipLaunchKernelGGL(k_tb, dim3(2048), dim3(256), 0, stream,
                       outD, outD + (size_t)TOT_, outD + 2 * (size_t)TOT_,
                       outD + 3 * (size_t)TOT_, out);
}

// Round 18
// 266.411 us; speedup vs baseline: 1.0796x; 1.0796x over previous
//
#include <hip/hip_runtime.h>

// UAG_RNN v18 (3rd resubmit; pod stiff-dense-novel-robot crash-looping,
//  kernel has never executed): v16 + LDS-staged ys.
//  R14: more-CUs-fewer-bytes was null -> below ~30KB/step the limit is
//  per-CU load DELIVERY. ys is 95% a copy of yr (row R-+1): v16 re-loads
//  it (16 instrs + 8KB L1 bytes/wave-step = 40% of delivered traffic).
//  Stage yr into a shared y-column LDS buffer (4 ds_write_b128), lgkm
//  barrier, read shifted row (4 ds_read_b128, 68-float pitch = 2-way
//  conflict-free). Bit-identical values; halo-outer lanes use zeroed pads
//  (inside the existing corruption-front margin). -48 VGPR.
// B=8, C=64, H=128, W=128.

#define B_ 8
#define C_ 64
#define H_ 128
#define W_ 128
#define HW_ (H_*W_)      // 16384
#define CHW_ (C_*HW_)    // 1048576
#define TOT_ (B_*CHW_)   // 8388608

typedef __attribute__((ext_vector_type(8))) short bfrag;
typedef __attribute__((ext_vector_type(4))) float f4_t;

__device__ inline unsigned short bfr(float f) {
    unsigned int u = __float_as_uint(f);
    u += 0x7fffu + ((u >> 16) & 1u);
    return (unsigned short)(u >> 16);
}
__device__ inline float b2f(unsigned short u) {
    return __uint_as_float(((unsigned int)u) << 16);
}
__device__ inline bfrag packf(float4 a, float4 b) {
    bfrag r;
    r[0]=(short)bfr(a.x); r[1]=(short)bfr(a.y); r[2]=(short)bfr(a.z); r[3]=(short)bfr(a.w);
    r[4]=(short)bfr(b.x); r[5]=(short)bfr(b.y); r[6]=(short)bfr(b.z); r[7]=(short)bfr(b.w);
    return r;
}
__device__ inline ushort4 pack4(float a, float b, float c, float d) {
    ushort4 r; r.x=bfr(a); r.y=bfr(b); r.z=bfr(c); r.w=bfr(d); return r;
}
__device__ inline unsigned int relu2(unsigned int w) {
    unsigned int lo = (w & 0x8000u) ? 0u : (w & 0xffffu);
    unsigned int hi = (w & 0x80000000u) ? 0u : (w & 0xffff0000u);
    return lo | hi;
}
__device__ inline uint4 relu8(uint4 v) {
    v.x = relu2(v.x); v.y = relu2(v.y); v.z = relu2(v.z); v.w = relu2(v.w);
    return v;
}

#define MFMA __builtin_amdgcn_mfma_f32_16x16x32_bf16

// lgkm-only barrier, NO memory clobber (v9/v12/v13/v16-proven): 0xC07F =
// vmcnt(63) expcnt(7) lgkmcnt(0). Orders LDS across waves; vmem in flight.
#define SBAR_LGKM() do { \
    __builtin_amdgcn_sched_barrier(0); \
    __builtin_amdgcn_s_waitcnt(0xC07F); \
    __builtin_amdgcn_s_barrier(); \
    __builtin_amdgcn_sched_barrier(0); \
} while (0)

// x NCHW fp32 -> x2 NHWC(h-major) bf16
// y NCHW fp32 -> y2 NHWC(h-major) fp32  AND  y2T NHWC(w-major) fp32
__global__ void k_prep(const float* __restrict__ x, const float* __restrict__ y,
                       float* __restrict__ y2, float* __restrict__ y2T,
                       unsigned short* __restrict__ x2) {
    __shared__ float t[64][65];
    int blk = blockIdx.x;
    int isx = blk >> 11; blk &= 2047;
    int b = blk >> 8, hw0 = (blk & 255) * 64;
    int cq = threadIdx.x >> 6, lo = threadIdx.x & 63;
    const float* ip = (isx ? x : y) + (size_t)b * CHW_;
#pragma unroll
    for (int p = 0; p < 16; p++) {
        int c = p * 4 + cq;
        t[c][lo] = ip[(size_t)c * HW_ + hw0 + lo];
    }
    __syncthreads();
    if (isx) {
        unsigned short* op = x2 + (size_t)b * CHW_;
#pragma unroll
        for (int p = 0; p < 16; p++) {
            int hw = p * 4 + cq;
            op[(size_t)(hw0 + hw) * 64 + lo] = bfr(t[lo][hw]);
        }
    } else {
        float* op = y2 + (size_t)b * CHW_;
        float* opT = y2T + (size_t)b * CHW_;
#pragma unroll
        for (int p = 0; p < 16; p++) {
            int hw = p * 4 + cq;
            int P = hw0 + hw;
            int h = P >> 7, w = P & 127;
            float v = t[lo][hw];
            op[(size_t)P * 64 + lo] = v;
            opT[(size_t)((w << 7) | h) * 64 + lo] = v;
        }
    }
}

// sum 4 fp32 NHWC(h-major) dir buffers -> out NCHW fp32
__global__ void k_tb(const float* __restrict__ i0, const float* __restrict__ i1,
                     const float* __restrict__ i2, const float* __restrict__ i3,
                     float* __restrict__ outp) {
    __shared__ float t[64][65];
    int blk = blockIdx.x;
    int b = blk >> 8, hw0 = (blk & 255) * 64;
    int cq = threadIdx.x >> 6, lo = threadIdx.x & 63;
    size_t bb = (size_t)b * CHW_;
#pragma unroll
    for (int p = 0; p < 16; p++) {
        int hw = p * 4 + cq;
        size_t s = bb + (size_t)(hw0 + hw) * 64 + lo;
        t[hw][lo] = i0[s] + i1[s] + i2[s] + i3[s];
    }
    __syncthreads();
    float* op = outp + bb;
#pragma unroll
    for (int p = 0; p < 16; p++) {
        int c = p * 4 + cq;
        op[(size_t)c * HW_ + hw0 + lo] = t[lo][c];
    }
}

// ---------------- row scans ----------------
struct PrefR { uint4 x0, x1; float4 yv[4]; };

__device__ __forceinline__ void row_step(
        int i, int s, int w0, int q, int n,
        const unsigned short* __restrict__ xb, const float* __restrict__ yb,
        unsigned short* __restrict__ dT,
        unsigned short (&stt)[2][16][72],
        const bfrag (&WaF)[4][2], const bfrag (&WbF)[4][2],
        const f4_t (&cA)[4], const f4_t (&cB)[4],
        PrefR& cur, PrefR& nxt) {
    int row = s ? 127 - i : i;
    int rd = (i - 1) & 1, wr = i & 1;

    bfrag fb0 = *(const bfrag*)&stt[rd][n][q * 8];
    bfrag fb1 = *(const bfrag*)&stt[rd][n][32 + q * 8];
    bfrag fa0 = *(const bfrag*)&cur.x0;
    bfrag fa1 = *(const bfrag*)&cur.x1;

    f4_t DA[4], DB[4];
#pragma unroll
    for (int mt = 0; mt < 4; mt++) {
        DA[mt] = MFMA(WaF[mt][0], fa0, cA[mt], 0, 0, 0);
        DA[mt] = MFMA(WaF[mt][1], fa1, DA[mt], 0, 0, 0);
        DB[mt] = MFMA(WbF[mt][0], fb0, cB[mt], 0, 0, 0);
        DB[mt] = MFMA(WbF[mt][1], fb1, DB[mt], 0, 0, 0);
    }

    if (i < 127) {
        int rowN = s ? 126 - i : i + 1;
        int yrowN = s ? rowN + 1 : rowN - 1;
        const unsigned short* sp = xb + (size_t)(rowN * 128 + w0 + n) * 64 + q * 8;
        nxt.x0 = *(const uint4*)sp;
        nxt.x1 = *(const uint4*)(sp + 32);
#pragma unroll
        for (int mt = 0; mt < 4; mt++)
            nxt.yv[mt] = *(const float4*)&yb[(size_t)(yrowN * 128 + w0 + n) * 64 + mt * 16 + q * 4];
    }

#pragma unroll
    for (int mt = 0; mt < 4; mt++) {
        float h0 = fmaxf(DA[mt][0] + DB[mt][0] * cur.yv[mt].x, 0.f);
        float h1 = fmaxf(DA[mt][1] + DB[mt][1] * cur.yv[mt].y, 0.f);
        float h2 = fmaxf(DA[mt][2] + DB[mt][2] * cur.yv[mt].z, 0.f);
        float h3 = fmaxf(DA[mt][3] + DB[mt][3] * cur.yv[mt].w, 0.f);
        ushort4 pk = pack4(h0, h1, h2, h3);
        *(ushort4*)&stt[wr][n][mt * 16 + q * 4] = pk;
        // w-major output: ((w)*128 + h)*64 + ch   (colscan reads columns!)
        *(ushort4*)&dT[(size_t)((w0 + n) * 128 + row) * 64 + mt * 16 + q * 4] = pk;
    }
}

// grid 128 = s(2) x b(8) x wb(8 of width 16). 1 wave/block.
__global__ __launch_bounds__(64, 1) void k_rowscan(
        const unsigned short* __restrict__ x2, const float* __restrict__ y2,
        const float* __restrict__ Wc, const float* __restrict__ bc,
        unsigned short* __restrict__ hsT, unsigned short* __restrict__ hnT) {
    int bid = blockIdx.x;
    int s = bid >> 6, b = (bid >> 3) & 7, wb = bid & 7;
    int w0 = wb * 16;
    int lane = threadIdx.x, q = lane >> 4, n = lane & 15;
    int ka = s ? 8 : 0, kb = ka + 1;

    bfrag WaF[4][2], WbF[4][2];
#pragma unroll
    for (int mt = 0; mt < 4; mt++)
#pragma unroll
        for (int kc = 0; kc < 2; kc++) {
            const float* wp = Wc + (size_t)(ka * 64 + mt * 16 + n) * 64 + kc * 32 + q * 8;
            WaF[mt][kc] = packf(*(const float4*)wp, *(const float4*)(wp + 4));
            const float* wq2 = Wc + (size_t)(kb * 64 + mt * 16 + n) * 64 + kc * 32 + q * 8;
            WbF[mt][kc] = packf(*(const float4*)wq2, *(const float4*)(wq2 + 4));
        }
    f4_t cA[4], cB[4];
#pragma unroll
    for (int mt = 0; mt < 4; mt++) {
        float4 ta = *(const float4*)&bc[ka * 64 + mt * 16 + q * 4];
        float4 tb = *(const float4*)&bc[kb * 64 + mt * 16 + q * 4];
        cA[mt] = f4_t{ta.x, ta.y, ta.z, ta.w};
        cB[mt] = f4_t{tb.x, tb.y, tb.z, tb.w};
    }

    const unsigned short* xb = x2 + (size_t)b * CHW_;
    const float* yb = y2 + (size_t)b * CHW_;
    unsigned short* dT = (s ? hnT : hsT) + (size_t)b * CHW_;

    __shared__ __align__(16) unsigned short stt[2][16][72];

    int row0 = s ? 127 : 0;
    {
        const unsigned short* sp = xb + (size_t)(row0 * 128 + w0 + n) * 64 + q * 16;
        uint4 v0 = *(const uint4*)sp;
        uint4 v1 = *(const uint4*)(sp + 8);
        if (s) { v0 = relu8(v0); v1 = relu8(v1); }
        *(uint4*)&stt[0][n][q * 16] = v0;
        *(uint4*)&stt[0][n][q * 16 + 8] = v1;
        unsigned short* op = dT + (size_t)((w0 + n) * 128 + row0) * 64 + q * 16;
        *(uint4*)op = v0;
        *(uint4*)(op + 8) = v1;
    }

    PrefR Pa, Pb;
    {
        int row1 = s ? 126 : 1;
        const unsigned short* sp = xb + (size_t)(row1 * 128 + w0 + n) * 64 + q * 8;
        Pa.x0 = *(const uint4*)sp;
        Pa.x1 = *(const uint4*)(sp + 32);
#pragma unroll
        for (int mt = 0; mt < 4; mt++)
            Pa.yv[mt] = *(const float4*)&yb[(size_t)(row0 * 128 + w0 + n) * 64 + mt * 16 + q * 4];
    }

    for (int i = 1; i < 127; i += 2) {
        row_step(i,     s, w0, q, n, xb, yb, dT, stt, WaF, WbF, cA, cB, Pa, Pb);
        row_step(i + 1, s, w0, q, n, xb, yb, dT, stt, WaF, WbF, cA, cB, Pb, Pa);
    }
    row_step(127, s, w0, q, n, xb, yb, dT, stt, WaF, WbF, cA, cB, Pa, Pb);
}

// ---------------- col scans (halo, LDS-staged ys) ----------------
// 4 blocks/chain x 3 waves. Block k: rows [base_row, base_row+48),
// base_row = down ? 32k-16 : 32k. Wave g owns 16 rows (g*16+n local).
// down: g0 = halo (above), g1/g2 owned. up: g0/g1 owned, g2 = halo (below).
// Halo refresh at j=16,...,112. Ring Pa/Pb/Pc (depth 2). ys gate comes
// from the LDS y-column buffer yst (staged from yr each step).
struct PrefC { uint4 b0, b1; float4 yr[4]; };

__device__ __forceinline__ void cpre(
        int p, int flip, int q, int Rc,
        const unsigned short* __restrict__ baseT, const float* __restrict__ yT,
        PrefC& dst) {
    if (p > 127) return;
    int cjP = flip ? 127 - p : p;
    int ycP = flip ? 128 - p : p - 1;
    const unsigned short* sp = baseT + (size_t)(cjP * 128 + Rc) * 64 + q * 8;
    dst.b0 = *(const uint4*)sp;
    dst.b1 = *(const uint4*)(sp + 32);
#pragma unroll
    for (int mt = 0; mt < 4; mt++)
        dst.yr[mt] = *(const float4*)&yT[(size_t)(ycP * 128 + Rc) * 64 + mt * 16 + q * 4];
}

__device__ __forceinline__ void cstep(
        int j, int pcol, int flip, int down, int k, int g, int base_row,
        int q, int n, float gmv,
        const unsigned short* __restrict__ baseT, const float* __restrict__ yT,
        float* __restrict__ oB,
        unsigned short (&stt)[2][50][72], float (&yst)[50][68],
        const bfrag (&WA)[4][2], const bfrag (&WB)[4][2], const bfrag (&WT)[4][2],
        const f4_t (&cAr)[4], const f4_t (&cBr)[4], const f4_t (&cTr)[4],
        unsigned int* __restrict__ flags, ushort4* __restrict__ seamD, int cidx,
        bool ownedW, bool pubW, bool rdrW,
        PrefC& cur, PrefC& nxt) {
    int cj = flip ? 127 - j : j;
    int rd = (j - 1) & 1, wr = j & 1;
    int R  = base_row + g * 16 + n;
    int Rc = R < 0 ? 0 : (R > 127 ? 127 : R);
    int L  = g * 16 + n + 1;
    int Lsy = down ? (L - 1) : (L + 1);
    float gT = ((down ? (R == 0) : (R == 127)) ? 0.f : gmv);
    bool syncstep = ((j & 15) == 0) && (j <= 112);

    // ---- issue stream loads for column pcol (= j+2), 2 steps of cover
    cpre(pcol, flip, q, Rc, baseT, yT, nxt);

    // ---- stage this step's yr into the shared y-column buffer
#pragma unroll
    for (int mt = 0; mt < 4; mt++)
        *(float4*)&yst[L][mt * 16 + q * 4] = cur.yr[mt];
    SBAR_LGKM();

    // ---- LDS state reads
    bfrag fb0 = *(const bfrag*)&stt[rd][L][q * 8];
    bfrag fb1 = *(const bfrag*)&stt[rd][L][32 + q * 8];
    int Ls = down ? (L - 1) : (L + 1);
    bfrag ft0 = *(const bfrag*)&stt[rd][Ls][q * 8];
    bfrag ft1 = *(const bfrag*)&stt[rd][Ls][32 + q * 8];
    bfrag fa0 = *(const bfrag*)&cur.b0;
    bfrag fa1 = *(const bfrag*)&cur.b1;

    // shifted y gate from LDS (bit-identical to a global ys load)
    float4 ysv[4];
#pragma unroll
    for (int mt = 0; mt < 4; mt++)
        ysv[mt] = *(const float4*)&yst[Lsy][mt * 16 + q * 4];

    f4_t DA[4], DB[4], DT[4];
#pragma unroll
    for (int mt = 0; mt < 4; mt++) {
        DA[mt] = MFMA(WA[mt][0], fa0, cAr[mt], 0, 0, 0);
        DA[mt] = MFMA(WA[mt][1], fa1, DA[mt], 0, 0, 0);
        DB[mt] = MFMA(WB[mt][0], fb0, cBr[mt], 0, 0, 0);
        DB[mt] = MFMA(WB[mt][1], fb1, DB[mt], 0, 0, 0);
        DT[mt] = MFMA(WT[mt][0], ft0, cTr[mt], 0, 0, 0);
        DT[mt] = MFMA(WT[mt][1], ft1, DT[mt], 0, 0, 0);
    }

    size_t slotP = ((size_t)(cidx * 4 + k) * 8 + (j >> 4)) - 1;  // publisher slot

    // ---- finalize: h = relu(DA + DB*yr + gT*(DT*ys))
#pragma unroll
    for (int mt = 0; mt < 4; mt++) {
        float4 yr4 = cur.yr[mt];
        float4 ys4 = ysv[mt];
        float h0 = fmaxf(DA[mt][0] + DB[mt][0] * yr4.x + gT * (DT[mt][0] * ys4.x), 0.f);
        float h1 = fmaxf(DA[mt][1] + DB[mt][1] * yr4.y + gT * (DT[mt][1] * ys4.y), 0.f);
        float h2 = fmaxf(DA[mt][2] + DB[mt][2] * yr4.z + gT * (DT[mt][2] * ys4.z), 0.f);
        float h3 = fmaxf(DA[mt][3] + DB[mt][3] * yr4.w + gT * (DT[mt][3] * ys4.w), 0.f);
        ushort4 pk = pack4(h0, h1, h2, h3);
        *(ushort4*)&stt[wr][L][mt * 16 + q * 4] = pk;
        if (ownedW)
            *(float4*)&oB[(size_t)(R * 128 + cj) * 64 + mt * 16 + q * 4] =
                make_float4(h0, h1, h2, h3);
        if (pubW && syncstep)
            seamD[slotP * 256 + n * 16 + mt * 4 + q] = pk;
    }

    // ---- halo refresh protocol (every 16 columns; amortized)
    if (syncstep) {
        if (pubW && n == 0 && q == 0)
            __hip_atomic_store(&flags[slotP], 1u, __ATOMIC_RELEASE,
                               __HIP_MEMORY_SCOPE_AGENT);
        if (rdrW) {
            int kk = down ? k - 1 : k + 1;
            size_t slotR = ((size_t)(cidx * 4 + kk) * 8 + (j >> 4)) - 1;
            unsigned int guard = 0;
            while (__hip_atomic_load(&flags[slotR], __ATOMIC_ACQUIRE,
                                     __HIP_MEMORY_SCOPE_AGENT) == 0u)
                if (++guard > (1u << 22)) break;
#pragma unroll
            for (int mt = 0; mt < 4; mt++) {
                ushort4 sv = seamD[slotR * 256 + n * 16 + mt * 4 + q];
                *(ushort4*)&stt[wr][L][mt * 16 + q * 4] = sv;
            }
        }
    }
    SBAR_LGKM();
}

// grid 128 = k(4) x d(4) x b(8); bid = k*32 + d*8 + b so a chain's 4 blocks
// share an XCD (bid mod 8 == b). 192 threads = 3 waves (1 group each).
__global__ __launch_bounds__(192, 1) void k_colscan(
        const float* __restrict__ y2T,
        const unsigned short* __restrict__ hsT, const unsigned short* __restrict__ hnT,
        const float* __restrict__ Wc, const float* __restrict__ bc,
        const float* __restrict__ gam,
        unsigned int* __restrict__ flags, ushort4* __restrict__ seamD,
        float* __restrict__ outD) {
    int bid = blockIdx.x;
    int k = bid >> 5, d = (bid >> 3) & 3, b = bid & 7;
    int tid = threadIdx.x;
    int g = tid >> 6, lane = tid & 63, q = lane >> 4, n = lane & 15;
    int down = (d < 2) ? 1 : 0;
    int flip = d & 1;
    int cidx = d * 8 + b;
    int base_row = down ? 32 * k - 16 : 32 * k;
    bool ownedW = down ? (g > 0) : (g < 2);
    bool pubW = down ? (g == 2 && k < 3) : (g == 0 && k > 0);
    bool rdrW = down ? (g == 0 && k > 0) : (g == 2 && k < 3);
    const unsigned short* baseT = ((d < 2) ? hsT : hnT) + (size_t)b * CHW_;
    int kt, ka, kb;
    if (d == 0)      { kt = 2;  ka = 3;  kb = 4;  }
    else if (d == 1) { kt = 5;  ka = 6;  kb = 7;  }
    else if (d == 2) { kt = 10; ka = 11; kb = 12; }
    else             { kt = 13; ka = 14; kb = 15; }
    float gmv = gam[d];

    bfrag WA[4][2], WB[4][2], WT[4][2];
#pragma unroll
    for (int mt = 0; mt < 4; mt++)
#pragma unroll
        for (int kc = 0; kc < 2; kc++) {
            const float* wa = Wc + (size_t)(ka * 64 + mt * 16 + n) * 64 + kc * 32 + q * 8;
            const float* wb = Wc + (size_t)(kb * 64 + mt * 16 + n) * 64 + kc * 32 + q * 8;
            const float* wt = Wc + (size_t)(kt * 64 + mt * 16 + n) * 64 + kc * 32 + q * 8;
            WA[mt][kc] = packf(*(const float4*)wa, *(const float4*)(wa + 4));
            WB[mt][kc] = packf(*(const float4*)wb, *(const float4*)(wb + 4));
            WT[mt][kc] = packf(*(const float4*)wt, *(const float4*)(wt + 4));
        }
    f4_t cAr[4], cBr[4], cTr[4];
#pragma unroll
    for (int mt = 0; mt < 4; mt++) {
        float4 ta = *(const float4*)&bc[ka * 64 + mt * 16 + q * 4];
        float4 tb = *(const float4*)&bc[kb * 64 + mt * 16 + q * 4];
        float4 tt = *(const float4*)&bc[kt * 64 + mt * 16 + q * 4];
        cAr[mt] = f4_t{ta.x, ta.y, ta.z, ta.w};
        cBr[mt] = f4_t{tb.x, tb.y, tb.z, tb.w};
        cTr[mt] = f4_t{tt.x, tt.y, tt.z, tt.w};
    }

    const float* yT = y2T + (size_t)b * CHW_;
    float* oB = outD + (size_t)d * TOT_ + (size_t)b * CHW_;

    int R = base_row + g * 16 + n;
    int Rc = R < 0 ? 0 : (R > 127 ? 127 : R);
    int L = g * 16 + n + 1;

    __shared__ __align__(16) unsigned short stt[2][50][72];  // pads at 0 and 49
    __shared__ __align__(16) float yst[50][68];              // pads at 0 and 49
    for (int idx = tid; idx < 2 * 2 * 72; idx += 192) {
        int buf = idx / 144, hi = (idx / 72) & 1, t = idx % 72;
        stt[buf][hi ? 49 : 0][t] = 0;
    }
    for (int idx = tid; idx < 2 * 68; idx += 192) {
        int hi = idx / 68, c = idx % 68;
        yst[hi ? 49 : 0][c] = 0.f;   // keep halo-edge ys finite
    }

    // ---- j = 0 : c0 = relu(base col0) for all 48 rows (halo incl.)
    int c0 = flip ? 127 : 0;
    {
        const unsigned short* sp = baseT + (size_t)(c0 * 128 + Rc) * 64 + q * 16;
        uint4 v0 = relu8(*(const uint4*)sp);
        uint4 v1 = relu8(*(const uint4*)(sp + 8));
        *(uint4*)&stt[0][L][q * 16] = v0;
        *(uint4*)&stt[0][L][q * 16 + 8] = v1;
        if (ownedW) {
            float* op = oB + (size_t)(R * 128 + c0) * 64 + q * 16;
            unsigned int w8[8] = {v0.x, v0.y, v0.z, v0.w, v1.x, v1.y, v1.z, v1.w};
#pragma unroll
            for (int t = 0; t < 8; t++) {
                op[2 * t]     = b2f((unsigned short)(w8[t] & 0xffffu));
                op[2 * t + 1] = b2f((unsigned short)(w8[t] >> 16));
            }
        }
    }

    // prefetch ring: Pa <- col 1, Pb <- col 2
    PrefC Pa, Pb, Pc;
    cpre(1, flip, q, Rc, baseT, yT, Pa);
    cpre(2, flip, q, Rc, baseT, yT, Pb);
    SBAR_LGKM();

    // steps j=1..126 in triples; j consumes set(j), issues set for j+2.
    for (int j = 1; j <= 124; j += 3) {
        cstep(j,     j + 2, flip, down, k, g, base_row, q, n, gmv,
              baseT, yT, oB, stt, yst, WA, WB, WT, cAr, cBr, cTr,
              flags, seamD, cidx, ownedW, pubW, rdrW, Pa, Pc);
        cstep(j + 1, j + 3, flip, down, k, g, base_row, q, n, gmv,
              baseT, yT, oB, stt, yst, WA, WB, WT, cAr, cBr, cTr,
              flags, seamD, cidx, ownedW, pubW, rdrW, Pb, Pa);
        cstep(j + 2, j + 4, flip, down, k, g, base_row, q, n, gmv,
              baseT, yT, oB, stt, yst, WA, WB, WT, cAr, cBr, cTr,
              flags, seamD, cidx, ownedW, pubW, rdrW, Pc, Pb);
    }
    // tail: j = 127 consumes Pa (filled by cstep(125)'s pcol=127)
    cstep(127, 129, flip, down, k, g, base_row, q, n, gmv,
          baseT, yT, oB, stt, yst, WA, WB, WT, cAr, cBr, cTr,
          flags, seamD, cidx, ownedW, pubW, rdrW, Pa, Pb);
}

extern "C" void kernel_launch(void* const* d_in, const int* in_sizes, int n_in,
                              void* d_out, int out_size, void* d_ws, size_t ws_size,
                              hipStream_t stream) {
    const float* x   = (const float*)d_in[0];
    const float* y   = (const float*)d_in[1];
    const float* Wc  = (const float*)d_in[2];
    const float* bc  = (const float*)d_in[3];
    const float* gam = (const float*)d_in[4];
    float* out = (float*)d_out;

    // ws layout: x2 bf16 (16.8M), y2 fp32 (33.6M), y2T fp32 (33.6M),
    // hsT/hnT bf16 (16.8M ea), outD fp32 x4 (134.2M). Seam flags (64KB) +
    // seam data (2MB) overlay x2 (dead after rowscan; memset stream-ordered).
    unsigned short* x2 = (unsigned short*)d_ws;
    float* y2  = (float*)d_ws + (size_t)TOT_ / 2;
    float* y2T = y2 + (size_t)TOT_;
    unsigned short* hsT = (unsigned short*)(y2T + (size_t)TOT_);
    unsigned short* hnT = hsT + (size_t)TOT_;
    float* outD = (float*)(hnT + (size_t)TOT_);
    unsigned int* flags = (unsigned int*)d_ws;                       // 4 KB used
    ushort4* seamD = (ushort4*)((char*)d_ws + 65536);                // 2 MB

    hipLaunchKernelGGL(k_prep, dim3(4096), dim3(256), 0, stream, x, y, y2, y2T, x2);
    hipLaunchKernelGGL(k_rowscan, dim3(128), dim3(64), 0, stream, x2, y2, Wc, bc, hsT, hnT);
    hipMemsetAsync(flags, 0, 65536, stream);
    hipLaunchKernelGGL(k_colscan, dim3(128), dim3(192), 0, stream,
                       y2T, hsT, hnT, Wc, bc, gam, flags, seamD, outD);
    hipLaunchKernelGGL(k_tb, dim3(2048), dim3(256), 0, stream,
                       outD, outD + (size_t)TOT_, outD + 2 * (size_t)TOT_,
                       outD + 3 * (size_t)TOT_, out);
}

// Round 19
// 252.963 us; speedup vs baseline: 1.1369x; 1.0532x over previous
//
#include <hip/hip_runtime.h>

// UAG_RNN v19: v18 + bf16 outD (output-side byte dedup).
//  R18 confirmed delivery-dedup (ys via LDS: 194->179us). Remaining
//  redundancy is the store path: colscan wrote fp32 outD (8KB/step) that
//  k_tb re-reads (134MB), yet the info content is already bf16 (pk, the
//  forward state, computed anyway). Store pk directly (stores halve,
//  WRITE -25%); k_tb reads bf16 (67MB, BW-bound ~halves). One extra bf16
//  rounding on OUTPUT only (not propagated).
// B=8, C=64, H=128, W=128.

#define B_ 8
#define C_ 64
#define H_ 128
#define W_ 128
#define HW_ (H_*W_)      // 16384
#define CHW_ (C_*HW_)    // 1048576
#define TOT_ (B_*CHW_)   // 8388608

typedef __attribute__((ext_vector_type(8))) short bfrag;
typedef __attribute__((ext_vector_type(4))) float f4_t;

__device__ inline unsigned short bfr(float f) {
    unsigned int u = __float_as_uint(f);
    u += 0x7fffu + ((u >> 16) & 1u);
    return (unsigned short)(u >> 16);
}
__device__ inline float b2f(unsigned short u) {
    return __uint_as_float(((unsigned int)u) << 16);
}
__device__ inline bfrag packf(float4 a, float4 b) {
    bfrag r;
    r[0]=(short)bfr(a.x); r[1]=(short)bfr(a.y); r[2]=(short)bfr(a.z); r[3]=(short)bfr(a.w);
    r[4]=(short)bfr(b.x); r[5]=(short)bfr(b.y); r[6]=(short)bfr(b.z); r[7]=(short)bfr(b.w);
    return r;
}
__device__ inline ushort4 pack4(float a, float b, float c, float d) {
    ushort4 r; r.x=bfr(a); r.y=bfr(b); r.z=bfr(c); r.w=bfr(d); return r;
}
__device__ inline unsigned int relu2(unsigned int w) {
    unsigned int lo = (w & 0x8000u) ? 0u : (w & 0xffffu);
    unsigned int hi = (w & 0x80000000u) ? 0u : (w & 0xffff0000u);
    return lo | hi;
}
__device__ inline uint4 relu8(uint4 v) {
    v.x = relu2(v.x); v.y = relu2(v.y); v.z = relu2(v.z); v.w = relu2(v.w);
    return v;
}

#define MFMA __builtin_amdgcn_mfma_f32_16x16x32_bf16

// lgkm-only barrier, NO memory clobber (v9/v12/v13/v16/v18-proven):
// 0xC07F = vmcnt(63) expcnt(7) lgkmcnt(0). Vmem stays in flight.
#define SBAR_LGKM() do { \
    __builtin_amdgcn_sched_barrier(0); \
    __builtin_amdgcn_s_waitcnt(0xC07F); \
    __builtin_amdgcn_s_barrier(); \
    __builtin_amdgcn_sched_barrier(0); \
} while (0)

// x NCHW fp32 -> x2 NHWC(h-major) bf16
// y NCHW fp32 -> y2 NHWC(h-major) fp32  AND  y2T NHWC(w-major) fp32
__global__ void k_prep(const float* __restrict__ x, const float* __restrict__ y,
                       float* __restrict__ y2, float* __restrict__ y2T,
                       unsigned short* __restrict__ x2) {
    __shared__ float t[64][65];
    int blk = blockIdx.x;
    int isx = blk >> 11; blk &= 2047;
    int b = blk >> 8, hw0 = (blk & 255) * 64;
    int cq = threadIdx.x >> 6, lo = threadIdx.x & 63;
    const float* ip = (isx ? x : y) + (size_t)b * CHW_;
#pragma unroll
    for (int p = 0; p < 16; p++) {
        int c = p * 4 + cq;
        t[c][lo] = ip[(size_t)c * HW_ + hw0 + lo];
    }
    __syncthreads();
    if (isx) {
        unsigned short* op = x2 + (size_t)b * CHW_;
#pragma unroll
        for (int p = 0; p < 16; p++) {
            int hw = p * 4 + cq;
            op[(size_t)(hw0 + hw) * 64 + lo] = bfr(t[lo][hw]);
        }
    } else {
        float* op = y2 + (size_t)b * CHW_;
        float* opT = y2T + (size_t)b * CHW_;
#pragma unroll
        for (int p = 0; p < 16; p++) {
            int hw = p * 4 + cq;
            int P = hw0 + hw;
            int h = P >> 7, w = P & 127;
            float v = t[lo][hw];
            op[(size_t)P * 64 + lo] = v;
            opT[(size_t)((w << 7) | h) * 64 + lo] = v;
        }
    }
}

// sum 4 bf16 NHWC(h-major) dir buffers -> out NCHW fp32
__global__ void k_tb(const unsigned short* __restrict__ i0,
                     const unsigned short* __restrict__ i1,
                     const unsigned short* __restrict__ i2,
                     const unsigned short* __restrict__ i3,
                     float* __restrict__ outp) {
    __shared__ float t[64][65];
    int blk = blockIdx.x;
    int b = blk >> 8, hw0 = (blk & 255) * 64;
    int tid = threadIdx.x;
    size_t bb = (size_t)b * CHW_;
    // phase 1: 4 iters x 16 positions; each thread loads ushort4 (4 ch)
    // from each dir buffer, sums in fp32 into t[pos][ch].
#pragma unroll
    for (int it = 0; it < 4; it++) {
        int pos = it * 16 + (tid >> 4);
        int ch4 = (tid & 15) * 4;
        size_t s = bb + (size_t)(hw0 + pos) * 64 + ch4;
        ushort4 a0 = *(const ushort4*)&i0[s];
        ushort4 a1 = *(const ushort4*)&i1[s];
        ushort4 a2 = *(const ushort4*)&i2[s];
        ushort4 a3 = *(const ushort4*)&i3[s];
        t[pos][ch4 + 0] = b2f(a0.x) + b2f(a1.x) + b2f(a2.x) + b2f(a3.x);
        t[pos][ch4 + 1] = b2f(a0.y) + b2f(a1.y) + b2f(a2.y) + b2f(a3.y);
        t[pos][ch4 + 2] = b2f(a0.z) + b2f(a1.z) + b2f(a2.z) + b2f(a3.z);
        t[pos][ch4 + 3] = b2f(a0.w) + b2f(a1.w) + b2f(a2.w) + b2f(a3.w);
    }
    __syncthreads();
    int cq = tid >> 6, lo = tid & 63;
    float* op = outp + bb;
#pragma unroll
    for (int p = 0; p < 16; p++) {
        int c = p * 4 + cq;
        op[(size_t)c * HW_ + hw0 + lo] = t[lo][c];
    }
}

// ---------------- row scans ----------------
struct PrefR { uint4 x0, x1; float4 yv[4]; };

__device__ __forceinline__ void row_step(
        int i, int s, int w0, int q, int n,
        const unsigned short* __restrict__ xb, const float* __restrict__ yb,
        unsigned short* __restrict__ dT,
        unsigned short (&stt)[2][16][72],
        const bfrag (&WaF)[4][2], const bfrag (&WbF)[4][2],
        const f4_t (&cA)[4], const f4_t (&cB)[4],
        PrefR& cur, PrefR& nxt) {
    int row = s ? 127 - i : i;
    int rd = (i - 1) & 1, wr = i & 1;

    bfrag fb0 = *(const bfrag*)&stt[rd][n][q * 8];
    bfrag fb1 = *(const bfrag*)&stt[rd][n][32 + q * 8];
    bfrag fa0 = *(const bfrag*)&cur.x0;
    bfrag fa1 = *(const bfrag*)&cur.x1;

    f4_t DA[4], DB[4];
#pragma unroll
    for (int mt = 0; mt < 4; mt++) {
        DA[mt] = MFMA(WaF[mt][0], fa0, cA[mt], 0, 0, 0);
        DA[mt] = MFMA(WaF[mt][1], fa1, DA[mt], 0, 0, 0);
        DB[mt] = MFMA(WbF[mt][0], fb0, cB[mt], 0, 0, 0);
        DB[mt] = MFMA(WbF[mt][1], fb1, DB[mt], 0, 0, 0);
    }

    if (i < 127) {
        int rowN = s ? 126 - i : i + 1;
        int yrowN = s ? rowN + 1 : rowN - 1;
        const unsigned short* sp = xb + (size_t)(rowN * 128 + w0 + n) * 64 + q * 8;
        nxt.x0 = *(const uint4*)sp;
        nxt.x1 = *(const uint4*)(sp + 32);
#pragma unroll
        for (int mt = 0; mt < 4; mt++)
            nxt.yv[mt] = *(const float4*)&yb[(size_t)(yrowN * 128 + w0 + n) * 64 + mt * 16 + q * 4];
    }

#pragma unroll
    for (int mt = 0; mt < 4; mt++) {
        float h0 = fmaxf(DA[mt][0] + DB[mt][0] * cur.yv[mt].x, 0.f);
        float h1 = fmaxf(DA[mt][1] + DB[mt][1] * cur.yv[mt].y, 0.f);
        float h2 = fmaxf(DA[mt][2] + DB[mt][2] * cur.yv[mt].z, 0.f);
        float h3 = fmaxf(DA[mt][3] + DB[mt][3] * cur.yv[mt].w, 0.f);
        ushort4 pk = pack4(h0, h1, h2, h3);
        *(ushort4*)&stt[wr][n][mt * 16 + q * 4] = pk;
        // w-major output: ((w)*128 + h)*64 + ch   (colscan reads columns!)
        *(ushort4*)&dT[(size_t)((w0 + n) * 128 + row) * 64 + mt * 16 + q * 4] = pk;
    }
}

// grid 128 = s(2) x b(8) x wb(8 of width 16). 1 wave/block.
__global__ __launch_bounds__(64, 1) void k_rowscan(
        const unsigned short* __restrict__ x2, const float* __restrict__ y2,
        const float* __restrict__ Wc, const float* __restrict__ bc,
        unsigned short* __restrict__ hsT, unsigned short* __restrict__ hnT) {
    int bid = blockIdx.x;
    int s = bid >> 6, b = (bid >> 3) & 7, wb = bid & 7;
    int w0 = wb * 16;
    int lane = threadIdx.x, q = lane >> 4, n = lane & 15;
    int ka = s ? 8 : 0, kb = ka + 1;

    bfrag WaF[4][2], WbF[4][2];
#pragma unroll
    for (int mt = 0; mt < 4; mt++)
#pragma unroll
        for (int kc = 0; kc < 2; kc++) {
            const float* wp = Wc + (size_t)(ka * 64 + mt * 16 + n) * 64 + kc * 32 + q * 8;
            WaF[mt][kc] = packf(*(const float4*)wp, *(const float4*)(wp + 4));
            const float* wq2 = Wc + (size_t)(kb * 64 + mt * 16 + n) * 64 + kc * 32 + q * 8;
            WbF[mt][kc] = packf(*(const float4*)wq2, *(const float4*)(wq2 + 4));
        }
    f4_t cA[4], cB[4];
#pragma unroll
    for (int mt = 0; mt < 4; mt++) {
        float4 ta = *(const float4*)&bc[ka * 64 + mt * 16 + q * 4];
        float4 tb = *(const float4*)&bc[kb * 64 + mt * 16 + q * 4];
        cA[mt] = f4_t{ta.x, ta.y, ta.z, ta.w};
        cB[mt] = f4_t{tb.x, tb.y, tb.z, tb.w};
    }

    const unsigned short* xb = x2 + (size_t)b * CHW_;
    const float* yb = y2 + (size_t)b * CHW_;
    unsigned short* dT = (s ? hnT : hsT) + (size_t)b * CHW_;

    __shared__ __align__(16) unsigned short stt[2][16][72];

    int row0 = s ? 127 : 0;
    {
        const unsigned short* sp = xb + (size_t)(row0 * 128 + w0 + n) * 64 + q * 16;
        uint4 v0 = *(const uint4*)sp;
        uint4 v1 = *(const uint4*)(sp + 8);
        if (s) { v0 = relu8(v0); v1 = relu8(v1); }
        *(uint4*)&stt[0][n][q * 16] = v0;
        *(uint4*)&stt[0][n][q * 16 + 8] = v1;
        unsigned short* op = dT + (size_t)((w0 + n) * 128 + row0) * 64 + q * 16;
        *(uint4*)op = v0;
        *(uint4*)(op + 8) = v1;
    }

    PrefR Pa, Pb;
    {
        int row1 = s ? 126 : 1;
        const unsigned short* sp = xb + (size_t)(row1 * 128 + w0 + n) * 64 + q * 8;
        Pa.x0 = *(const uint4*)sp;
        Pa.x1 = *(const uint4*)(sp + 32);
#pragma unroll
        for (int mt = 0; mt < 4; mt++)
            Pa.yv[mt] = *(const float4*)&yb[(size_t)(row0 * 128 + w0 + n) * 64 + mt * 16 + q * 4];
    }

    for (int i = 1; i < 127; i += 2) {
        row_step(i,     s, w0, q, n, xb, yb, dT, stt, WaF, WbF, cA, cB, Pa, Pb);
        row_step(i + 1, s, w0, q, n, xb, yb, dT, stt, WaF, WbF, cA, cB, Pb, Pa);
    }
    row_step(127, s, w0, q, n, xb, yb, dT, stt, WaF, WbF, cA, cB, Pa, Pb);
}

// ---------------- col scans (halo, LDS-staged ys, bf16 out) ----------
// 4 blocks/chain x 3 waves. Block k: rows [base_row, base_row+48),
// base_row = down ? 32k-16 : 32k. Wave g owns 16 rows (g*16+n local).
// down: g0 = halo (above), g1/g2 owned. up: g0/g1 owned, g2 = halo (below).
// Halo refresh at j=16,...,112. Ring Pa/Pb/Pc (depth 2). ys from yst LDS.
struct PrefC { uint4 b0, b1; float4 yr[4]; };

__device__ __forceinline__ void cpre(
        int p, int flip, int q, int Rc,
        const unsigned short* __restrict__ baseT, const float* __restrict__ yT,
        PrefC& dst) {
    if (p > 127) return;
    int cjP = flip ? 127 - p : p;
    int ycP = flip ? 128 - p : p - 1;
    const unsigned short* sp = baseT + (size_t)(cjP * 128 + Rc) * 64 + q * 8;
    dst.b0 = *(const uint4*)sp;
    dst.b1 = *(const uint4*)(sp + 32);
#pragma unroll
    for (int mt = 0; mt < 4; mt++)
        dst.yr[mt] = *(const float4*)&yT[(size_t)(ycP * 128 + Rc) * 64 + mt * 16 + q * 4];
}

__device__ __forceinline__ void cstep(
        int j, int pcol, int flip, int down, int k, int g, int base_row,
        int q, int n, float gmv,
        const unsigned short* __restrict__ baseT, const float* __restrict__ yT,
        unsigned short* __restrict__ oB,
        unsigned short (&stt)[2][50][72], float (&yst)[50][68],
        const bfrag (&WA)[4][2], const bfrag (&WB)[4][2], const bfrag (&WT)[4][2],
        const f4_t (&cAr)[4], const f4_t (&cBr)[4], const f4_t (&cTr)[4],
        unsigned int* __restrict__ flags, ushort4* __restrict__ seamD, int cidx,
        bool ownedW, bool pubW, bool rdrW,
        PrefC& cur, PrefC& nxt) {
    int cj = flip ? 127 - j : j;
    int rd = (j - 1) & 1, wr = j & 1;
    int R  = base_row + g * 16 + n;
    int Rc = R < 0 ? 0 : (R > 127 ? 127 : R);
    int L  = g * 16 + n + 1;
    int Lsy = down ? (L - 1) : (L + 1);
    float gT = ((down ? (R == 0) : (R == 127)) ? 0.f : gmv);
    bool syncstep = ((j & 15) == 0) && (j <= 112);

    // ---- issue stream loads for column pcol (= j+2), 2 steps of cover
    cpre(pcol, flip, q, Rc, baseT, yT, nxt);

    // ---- stage this step's yr into the shared y-column buffer
#pragma unroll
    for (int mt = 0; mt < 4; mt++)
        *(float4*)&yst[L][mt * 16 + q * 4] = cur.yr[mt];
    SBAR_LGKM();

    // ---- LDS state reads
    bfrag fb0 = *(const bfrag*)&stt[rd][L][q * 8];
    bfrag fb1 = *(const bfrag*)&stt[rd][L][32 + q * 8];
    int Ls = down ? (L - 1) : (L + 1);
    bfrag ft0 = *(const bfrag*)&stt[rd][Ls][q * 8];
    bfrag ft1 = *(const bfrag*)&stt[rd][Ls][32 + q * 8];
    bfrag fa0 = *(const bfrag*)&cur.b0;
    bfrag fa1 = *(const bfrag*)&cur.b1;

    // shifted y gate from LDS (bit-identical to a global ys load)
    float4 ysv[4];
#pragma unroll
    for (int mt = 0; mt < 4; mt++)
        ysv[mt] = *(const float4*)&yst[Lsy][mt * 16 + q * 4];

    f4_t DA[4], DB[4], DT[4];
#pragma unroll
    for (int mt = 0; mt < 4; mt++) {
        DA[mt] = MFMA(WA[mt][0], fa0, cAr[mt], 0, 0, 0);
        DA[mt] = MFMA(WA[mt][1], fa1, DA[mt], 0, 0, 0);
        DB[mt] = MFMA(WB[mt][0], fb0, cBr[mt], 0, 0, 0);
        DB[mt] = MFMA(WB[mt][1], fb1, DB[mt], 0, 0, 0);
        DT[mt] = MFMA(WT[mt][0], ft0, cTr[mt], 0, 0, 0);
        DT[mt] = MFMA(WT[mt][1], ft1, DT[mt], 0, 0, 0);
    }

    size_t slotP = ((size_t)(cidx * 4 + k) * 8 + (j >> 4)) - 1;  // publisher slot

    // ---- finalize: h = relu(DA + DB*yr + gT*(DT*ys)); store bf16 pk.
#pragma unroll
    for (int mt = 0; mt < 4; mt++) {
        float4 yr4 = cur.yr[mt];
        float4 ys4 = ysv[mt];
        float h0 = fmaxf(DA[mt][0] + DB[mt][0] * yr4.x + gT * (DT[mt][0] * ys4.x), 0.f);
        float h1 = fmaxf(DA[mt][1] + DB[mt][1] * yr4.y + gT * (DT[mt][1] * ys4.y), 0.f);
        float h2 = fmaxf(DA[mt][2] + DB[mt][2] * yr4.z + gT * (DT[mt][2] * ys4.z), 0.f);
        float h3 = fmaxf(DA[mt][3] + DB[mt][3] * yr4.w + gT * (DT[mt][3] * ys4.w), 0.f);
        ushort4 pk = pack4(h0, h1, h2, h3);
        *(ushort4*)&stt[wr][L][mt * 16 + q * 4] = pk;
        if (ownedW)
            *(ushort4*)&oB[(size_t)(R * 128 + cj) * 64 + mt * 16 + q * 4] = pk;
        if (pubW && syncstep)
            seamD[slotP * 256 + n * 16 + mt * 4 + q] = pk;
    }

    // ---- halo refresh protocol (every 16 columns; amortized)
    if (syncstep) {
        if (pubW && n == 0 && q == 0)
            __hip_atomic_store(&flags[slotP], 1u, __ATOMIC_RELEASE,
                               __HIP_MEMORY_SCOPE_AGENT);
        if (rdrW) {
            int kk = down ? k - 1 : k + 1;
            size_t slotR = ((size_t)(cidx * 4 + kk) * 8 + (j >> 4)) - 1;
            unsigned int guard = 0;
            while (__hip_atomic_load(&flags[slotR], __ATOMIC_ACQUIRE,
                                     __HIP_MEMORY_SCOPE_AGENT) == 0u)
                if (++guard > (1u << 22)) break;
#pragma unroll
            for (int mt = 0; mt < 4; mt++) {
                ushort4 sv = seamD[slotR * 256 + n * 16 + mt * 4 + q];
                *(ushort4*)&stt[wr][L][mt * 16 + q * 4] = sv;
            }
        }
    }
    SBAR_LGKM();
}

// grid 128 = k(4) x d(4) x b(8); bid = k*32 + d*8 + b so a chain's 4 blocks
// share an XCD (bid mod 8 == b). 192 threads = 3 waves (1 group each).
__global__ __launch_bounds__(192, 1) void k_colscan(
        const float* __restrict__ y2T,
        const unsigned short* __restrict__ hsT, const unsigned short* __restrict__ hnT,
        const float* __restrict__ Wc, const float* __restrict__ bc,
        const float* __restrict__ gam,
        unsigned int* __restrict__ flags, ushort4* __restrict__ seamD,
        unsigned short* __restrict__ outD) {
    int bid = blockIdx.x;
    int k = bid >> 5, d = (bid >> 3) & 3, b = bid & 7;
    int tid = threadIdx.x;
    int g = tid >> 6, lane = tid & 63, q = lane >> 4, n = lane & 15;
    int down = (d < 2) ? 1 : 0;
    int flip = d & 1;
    int cidx = d * 8 + b;
    int base_row = down ? 32 * k - 16 : 32 * k;
    bool ownedW = down ? (g > 0) : (g < 2);
    bool pubW = down ? (g == 2 && k < 3) : (g == 0 && k > 0);
    bool rdrW = down ? (g == 0 && k > 0) : (g == 2 && k < 3);
    const unsigned short* baseT = ((d < 2) ? hsT : hnT) + (size_t)b * CHW_;
    int kt, ka, kb;
    if (d == 0)      { kt = 2;  ka = 3;  kb = 4;  }
    else if (d == 1) { kt = 5;  ka = 6;  kb = 7;  }
    else if (d == 2) { kt = 10; ka = 11; kb = 12; }
    else             { kt = 13; ka = 14; kb = 15; }
    float gmv = gam[d];

    bfrag WA[4][2], WB[4][2], WT[4][2];
#pragma unroll
    for (int mt = 0; mt < 4; mt++)
#pragma unroll
        for (int kc = 0; kc < 2; kc++) {
            const float* wa = Wc + (size_t)(ka * 64 + mt * 16 + n) * 64 + kc * 32 + q * 8;
            const float* wb = Wc + (size_t)(kb * 64 + mt * 16 + n) * 64 + kc * 32 + q * 8;
            const float* wt = Wc + (size_t)(kt * 64 + mt * 16 + n) * 64 + kc * 32 + q * 8;
            WA[mt][kc] = packf(*(const float4*)wa, *(const float4*)(wa + 4));
            WB[mt][kc] = packf(*(const float4*)wb, *(const float4*)(wb + 4));
            WT[mt][kc] = packf(*(const float4*)wt, *(const float4*)(wt + 4));
        }
    f4_t cAr[4], cBr[4], cTr[4];
#pragma unroll
    for (int mt = 0; mt < 4; mt++) {
        float4 ta = *(const float4*)&bc[ka * 64 + mt * 16 + q * 4];
        float4 tb = *(const float4*)&bc[kb * 64 + mt * 16 + q * 4];
        float4 tt = *(const float4*)&bc[kt * 64 + mt * 16 + q * 4];
        cAr[mt] = f4_t{ta.x, ta.y, ta.z, ta.w};
        cBr[mt] = f4_t{tb.x, tb.y, tb.z, tb.w};
        cTr[mt] = f4_t{tt.x, tt.y, tt.z, tt.w};
    }

    const float* yT = y2T + (size_t)b * CHW_;
    unsigned short* oB = outD + (size_t)d * TOT_ + (size_t)b * CHW_;

    int R = base_row + g * 16 + n;
    int Rc = R < 0 ? 0 : (R > 127 ? 127 : R);
    int L = g * 16 + n + 1;

    __shared__ __align__(16) unsigned short stt[2][50][72];  // pads at 0 and 49
    __shared__ __align__(16) float yst[50][68];              // pads at 0 and 49
    for (int idx = tid; idx < 2 * 2 * 72; idx += 192) {
        int buf = idx / 144, hi = (idx / 72) & 1, t = idx % 72;
        stt[buf][hi ? 49 : 0][t] = 0;
    }
    for (int idx = tid; idx < 2 * 68; idx += 192) {
        int hi = idx / 68, c = idx % 68;
        yst[hi ? 49 : 0][c] = 0.f;   // keep halo-edge ys finite
    }

    // ---- j = 0 : c0 = relu(base col0) for all 48 rows (halo incl.)
    int c0 = flip ? 127 : 0;
    {
        const unsigned short* sp = baseT + (size_t)(c0 * 128 + Rc) * 64 + q * 16;
        uint4 v0 = relu8(*(const uint4*)sp);
        uint4 v1 = relu8(*(const uint4*)(sp + 8));
        *(uint4*)&stt[0][L][q * 16] = v0;
        *(uint4*)&stt[0][L][q * 16 + 8] = v1;
        if (ownedW) {
            unsigned short* op = oB + (size_t)(R * 128 + c0) * 64 + q * 16;
            *(uint4*)op = v0;
            *(uint4*)(op + 8) = v1;
        }
    }

    // prefetch ring: Pa <- col 1, Pb <- col 2
    PrefC Pa, Pb, Pc;
    cpre(1, flip, q, Rc, baseT, yT, Pa);
    cpre(2, flip, q, Rc, baseT, yT, Pb);
    SBAR_LGKM();

    // steps j=1..126 in triples; j consumes set(j), issues set for j+2.
    for (int j = 1; j <= 124; j += 3) {
        cstep(j,     j + 2, flip, down, k, g, base_row, q, n, gmv,
              baseT, yT, oB, stt, yst, WA, WB, WT, cAr, cBr, cTr,
              flags, seamD, cidx, ownedW, pubW, rdrW, Pa, Pc);
        cstep(j + 1, j + 3, flip, down, k, g, base_row, q, n, gmv,
              baseT, yT, oB, stt, yst, WA, WB, WT, cAr, cBr, cTr,
              flags, seamD, cidx, ownedW, pubW, rdrW, Pb, Pa);
        cstep(j + 2, j + 4, flip, down, k, g, base_row, q, n, gmv,
              baseT, yT, oB, stt, yst, WA, WB, WT, cAr, cBr, cTr,
              flags, seamD, cidx, ownedW, pubW, rdrW, Pc, Pb);
    }
    // tail: j = 127 consumes Pa (filled by cstep(125)'s pcol=127)
    cstep(127, 129, flip, down, k, g, base_row, q, n, gmv,
          baseT, yT, oB, stt, yst, WA, WB, WT, cAr, cBr, cTr,
          flags, seamD, cidx, ownedW, pubW, rdrW, Pa, Pb);
}

extern "C" void kernel_launch(void* const* d_in, const int* in_sizes, int n_in,
                              void* d_out, int out_size, void* d_ws, size_t ws_size,
                              hipStream_t stream) {
    const float* x   = (const float*)d_in[0];
    const float* y   = (const float*)d_in[1];
    const float* Wc  = (const float*)d_in[2];
    const float* bc  = (const float*)d_in[3];
    const float* gam = (const float*)d_in[4];
    float* out = (float*)d_out;

    // ws layout: x2 bf16 (16.8M), y2 fp32 (33.6M), y2T fp32 (33.6M),
    // hsT/hnT bf16 (16.8M ea), outD bf16 x4 (67M). Seam flags (64KB) +
    // seam data (2MB) overlay x2 (dead after rowscan; memset stream-ordered).
    unsigned short* x2 = (unsigned short*)d_ws;
    float* y2  = (float*)d_ws + (size_t)TOT_ / 2;
    float* y2T = y2 + (size_t)TOT_;
    unsigned short* hsT = (unsigned short*)(y2T + (size_t)TOT_);
    unsigned short* hnT = hsT + (size_t)TOT_;
    unsigned short* outD = hnT + (size_t)TOT_;
    unsigned int* flags = (unsigned int*)d_ws;                       // 4 KB used
    ushort4* seamD = (ushort4*)((char*)d_ws + 65536);                // 2 MB

    hipLaunchKernelGGL(k_prep, dim3(4096), dim3(256), 0, stream, x, y, y2, y2T, x2);
    hipLaunchKernelGGL(k_rowscan, dim3(128), dim3(64), 0, stream, x2, y2, Wc, bc, hsT, hnT);
    hipMemsetAsync(flags, 0, 65536, stream);
    hipLaunchKernelGGL(k_colscan, dim3(128), dim3(192), 0, stream,
                       y2T, hsT, hnT, Wc, bc, gam, flags, seamD, outD);
    hipLaunchKernelGGL(k_tb, dim3(2048), dim3(256), 0, stream,
                       outD, outD + (size_t)TOT_, outD + 2 * (size_t)TOT_,
                       outD + 3 * (size_t)TOT_, out);
}